// Round 6
// baseline (212.182 us; speedup 1.0000x reference)
//
#include <hip/hip_runtime.h>

// Problem constants (fixed by the reference)
#define B_     32
#define C_IN_  512
#define H_     56
#define W_     56
#define HW_    (H_ * W_)        // 3136
#define C_ENC_ 64
#define K_     256
#define BHW_   (B_ * HW_)       // 100352
#define PTS_ROW_ (3 + C_ENC_)   // 67

// ---------------------------------------------------------------------------
// k1: transpose conv_w [C_ENC, C_IN] -> Wt [C_IN, C_ENC]
// ---------------------------------------------------------------------------
__global__ __launch_bounds__(256) void k_transpose_w(
        const float* __restrict__ w, float* __restrict__ wt) {
    int i = blockIdx.x * 256 + threadIdx.x;          // 0 .. 32767
    if (i < C_ENC_ * C_IN_) {
        int o = i / C_IN_;
        int c = i % C_IN_;
        wt[c * C_ENC_ + o] = w[i];
    }
}

// 16 channels of FMA against a ready x-register block, W via wave-uniform
// scalar reads in 4-channel sub-blocks (64 SGPRs live at a time).
#define FMA16_(XREG, CBASE)                                            \
    _Pragma("unroll")                                                  \
    for (int q = 0; q < 4; ++q) {                                      \
        _Pragma("unroll")                                              \
        for (int u = 0; u < 4; ++u) {                                  \
            _Pragma("unroll")                                          \
            for (int o = 0; o < 16; ++o)                               \
                acc[o] = fmaf(XREG[q * 4 + u],                         \
                              wg[((CBASE) + q * 4 + u) * C_ENC_ + o],  \
                              acc[o]);                                 \
        }                                                              \
    }

// ---------------------------------------------------------------------------
// k2 v6: 1x1 conv + norm + feats store — register ping-pong streaming.
// v5's per-step LDS pipeline serialized on 32x(vmcnt+2 barriers): VALUBusy
// fell to 31%, yet 31% x 149us ~= 46us == the fp32 FMA floor -> the FMA work
// was already optimal, the barriers were the waste. v6:
//  - NO LDS for x, NO barriers in the K-loop: per-wave independent streaming
//  - ping-pong 16-deep x prefetch (two static half-bodies, no ring index,
//    no copy movs): issue->use distance = 512 wave-cycles -> at 2-3 resident
//    waves/SIMD = 1-1.5k cy wall >= 900 cy HBM-miss latency
//  - VGPR est ~56 (acc16 + xa16 + xb16 + addr): under the 64-VGPR occupancy
//    step, no launch_bounds cap (v4's (256,8) squeezed to 28 and broke
//    the prefetch depth)
// NUMERICS: per-(pixel,o) chain (bias, c-ascending fmaf) bit-identical to
// all passing rounds -> feats bit-identical. Norm = 4 group partials
// (o-ascending, then g-ascending) — identical to v5 which passed.
// ---------------------------------------------------------------------------
__global__ __launch_bounds__(256) void k_conv_norm(
        const float* __restrict__ F, const float* __restrict__ wt,
        const float* __restrict__ bias, float* __restrict__ norms,
        float* __restrict__ feats) {
    __shared__ float nrmp[64][4];                    // 1 KB only

    int t = threadIdx.x;
    int pix_l = t & 63;
    int g = __builtin_amdgcn_readfirstlane(t >> 6);  // 0..3, wave-uniform
    int pb = blockIdx.x;                             // 0..1567
    int b = pb / 49;                                 // 3136/64 = 49
    int pix0 = (pb % 49) * 64;

    const float* f  = F + (size_t)b * (C_IN_ * HW_) + pix0 + pix_l;
    const float* wg = wt + g * 16;                   // wt layout [c][64]

    float acc[16];
    #pragma unroll
    for (int o = 0; o < 16; ++o) acc[o] = bias[g * 16 + o];

    float xa[16], xb[16];
    #pragma unroll
    for (int u = 0; u < 16; ++u) xa[u] = f[(size_t)u * HW_];

    // 16 outer iters of 32 channels; last xa-prefetch wraps to c=0 (discarded)
    for (int c0 = 0; c0 < C_IN_; c0 += 32) {
        // half A: prefetch xb = c0+16..c0+31, FMA xa (c0..c0+15)
        #pragma unroll
        for (int u = 0; u < 16; ++u)
            xb[u] = f[(size_t)(c0 + 16 + u) * HW_];
        FMA16_(xa, c0)
        // half B: prefetch xa = c0+32..c0+47 (wrap at end), FMA xb
        int cn = (c0 + 32) & (C_IN_ - 1);
        #pragma unroll
        for (int u = 0; u < 16; ++u)
            xa[u] = f[(size_t)(cn + u) * HW_];
        FMA16_(xb, c0 + 16)
    }

    // feats store: [b][o][pix] -> 16 coalesced dword stores
    #pragma unroll
    for (int o = 0; o < 16; ++o)
        feats[(size_t)(b * C_ENC_ + g * 16 + o) * HW_ + pix0 + pix_l] = acc[o];

    // norm: per-group partial (o ascending), then 4 partials g-ascending
    float p = 0.0f;
    #pragma unroll
    for (int o = 0; o < 16; ++o) p = fmaf(acc[o], acc[o], p);
    nrmp[pix_l][g] = p;
    __syncthreads();

    if (t < 64) {
        float nrm = ((nrmp[t][0] + nrmp[t][1]) + nrmp[t][2]) + nrmp[t][3];
        norms[b * HW_ + pix0 + t] = nrm;
    }
}

// ---------------------------------------------------------------------------
// k3 v2 (unchanged, passed R3-R5): radix-select exact 256th-largest key,
// compact >= T, bitonic-sort 512 -> exact jax.lax.top_k order.
// Also writes the full sw plane.
// ---------------------------------------------------------------------------
__global__ __launch_bounds__(512) void k_topk(
        const float* __restrict__ norms, unsigned int* __restrict__ topk,
        float* __restrict__ sw_out) {
    __shared__ unsigned int keys[HW_];               // 12.25 KB
    __shared__ unsigned int hist[256];
    __shared__ unsigned long long sortbuf[512];      // 4 KB
    __shared__ unsigned int s_prefix, s_need, s_cnt;
    __shared__ unsigned char flags[HW_];

    int b = blockIdx.x;
    int t = threadIdx.x;
    const float* nb = norms + b * HW_;

    for (int i = t; i < HW_; i += 512) {
        keys[i] = __float_as_uint(nb[i]);
        flags[i] = 0;
    }
    if (t == 0) { s_prefix = 0u; s_need = K_; s_cnt = 0u; }
    for (int i = t; i < 512; i += 512) sortbuf[i] = ~0ULL;

    for (int r = 0; r < 4; ++r) {
        if (t < 256) hist[t] = 0u;
        __syncthreads();
        unsigned int pfx = s_prefix;
        int shift = 24 - 8 * r;
        for (int i = t; i < HW_; i += 512) {
            unsigned int k = keys[i];
            bool ok = (r == 0) || ((k >> (32 - 8 * r)) == pfx);
            if (ok) atomicAdd(&hist[(k >> shift) & 0xFFu], 1u);
        }
        __syncthreads();
        if (t < 64) {                                // wave 0: suffix-scan
            unsigned int h0 = hist[4 * t + 0];
            unsigned int h1 = hist[4 * t + 1];
            unsigned int h2 = hist[4 * t + 2];
            unsigned int h3 = hist[4 * t + 3];
            unsigned int tot = h0 + h1 + h2 + h3;
            unsigned int suf = tot;
            #pragma unroll
            for (int off = 1; off < 64; off <<= 1) {
                unsigned int v = __shfl_down(suf, off);
                suf += (t + off < 64) ? v : 0u;
            }
            unsigned int g0 = suf;
            unsigned int g1 = suf - h0;
            unsigned int g2 = g1 - h1;
            unsigned int g3 = g2 - h2;
            unsigned int g4 = g3 - h3;
            unsigned int need = s_need;
            if (g0 >= need && g1 < need) { s_prefix = (pfx << 8) | (4u*t+0u); s_need = need - g1; }
            if (g1 >= need && g2 < need) { s_prefix = (pfx << 8) | (4u*t+1u); s_need = need - g2; }
            if (g2 >= need && g3 < need) { s_prefix = (pfx << 8) | (4u*t+2u); s_need = need - g3; }
            if (g3 >= need && g4 < need) { s_prefix = (pfx << 8) | (4u*t+3u); s_need = need - g4; }
        }
        __syncthreads();
    }
    unsigned int T = s_prefix;

    for (int i = t; i < HW_; i += 512) {
        unsigned int k = keys[i];
        if (k >= T) {
            unsigned int pos = atomicAdd(&s_cnt, 1u);
            if (pos < 512)
                sortbuf[pos] = ((unsigned long long)(~k) << 32) | (unsigned int)i;
        }
    }
    __syncthreads();

    for (int kk = 2; kk <= 512; kk <<= 1) {
        for (int j = kk >> 1; j > 0; j >>= 1) {
            int ixj = t ^ j;
            if (ixj > t) {
                unsigned long long a = sortbuf[t], c = sortbuf[ixj];
                bool up = ((t & kk) == 0);
                if ((a > c) == up) { sortbuf[t] = c; sortbuf[ixj] = a; }
            }
            __syncthreads();
        }
    }

    if (t < K_) {
        unsigned long long e = sortbuf[t];
        unsigned int idx = (unsigned int)(e & 0xFFFFFFFFu);
        topk[b * K_ + t] = idx;
        flags[idx] = 1;
    }
    __syncthreads();

    float* swb = sw_out + b * HW_;
    for (int i = t; i < HW_; i += 512)
        swb[i] = flags[i] ? 1.0f : 0.0f;
}

// ---------------------------------------------------------------------------
// k4 v2 (unchanged): pure gather. One wave per (b,k): lane o reads
// feats[b][o][p], writes the 67-float points row.
// ---------------------------------------------------------------------------
__global__ __launch_bounds__(64) void k_points(
        const float* __restrict__ feats, const unsigned int* __restrict__ topk,
        float* __restrict__ points) {
    int bk = blockIdx.x;                             // 0 .. B*K-1
    int b = bk >> 8;                                 // K = 256
    int o = threadIdx.x;
    unsigned int p = topk[bk];

    float v = feats[(size_t)(b * C_ENC_ + o) * HW_ + p];
    float* row = points + (size_t)bk * PTS_ROW_;
    row[3 + o] = v;
    if (o == 0) {
        row[0] = (float)(p % W_);                    // abs_ (x)
        row[1] = (float)(p / W_);                    // ord_ (y)
        row[2] = 0.0f;                               // depth
    }
}

// ---------------------------------------------------------------------------
// k5 v2 (unchanged): x_out[b][o] = mean over K of feats[b][o][idx_k],
// k ascending (reference order). Indices staged in LDS.
// ---------------------------------------------------------------------------
__global__ __launch_bounds__(64) void k_xout(
        const float* __restrict__ feats, const unsigned int* __restrict__ topk,
        float* __restrict__ xout) {
    __shared__ unsigned int sidx[K_];
    int b = blockIdx.x;
    int t = threadIdx.x;
    for (int r = t; r < K_; r += 64) sidx[r] = topk[b * K_ + r];
    __syncthreads();

    const float* fb = feats + (size_t)(b * C_ENC_ + t) * HW_;
    float s = 0.0f;
    #pragma unroll 8
    for (int k = 0; k < K_; ++k) s += fb[sidx[k]];
    xout[b * C_ENC_ + t] = s * (1.0f / K_);
}

// ---------------------------------------------------------------------------
extern "C" void kernel_launch(void* const* d_in, const int* in_sizes, int n_in,
                              void* d_out, int out_size, void* d_ws, size_t ws_size,
                              hipStream_t stream) {
    const float* F    = (const float*)d_in[0];       // [B, C_IN, H, W]
    const float* w    = (const float*)d_in[1];       // [C_ENC, C_IN]
    const float* bias = (const float*)d_in[2];       // [C_ENC]

    float* out    = (float*)d_out;
    float* xout   = out;                             // [B, C_ENC]      (2048)
    float* sw     = out + B_ * C_ENC_;               // [B, 1, H, W]    (100352)
    float* points = sw + BHW_;                       // [B, K, 67]      (548864)

    // workspace: feats [B,64,HW] 25.7MB | Wt 128KB | norms 392KB | topk 32KB
    float* feats         = (float*)d_ws;
    float* wt            = feats + (size_t)B_ * C_ENC_ * HW_;
    float* norms         = wt + C_IN_ * C_ENC_;
    unsigned int* topk   = (unsigned int*)(norms + BHW_);

    k_transpose_w<<<128, 256, 0, stream>>>(w, wt);
    k_conv_norm  <<<BHW_ / 64, 256, 0, stream>>>(F, wt, bias, norms, feats);
    k_topk       <<<B_, 512, 0, stream>>>(norms, topk, sw);
    k_points     <<<B_ * K_, 64, 0, stream>>>(feats, topk, points);
    k_xout       <<<B_, 64, 0, stream>>>(feats, topk, xout);
}

// Round 7
// 161.713 us; speedup vs baseline: 1.3121x; 1.3121x over previous
//
#include <hip/hip_runtime.h>

// Problem constants (fixed by the reference)
#define B_     32
#define C_IN_  512
#define H_     56
#define W_     56
#define HW_    (H_ * W_)        // 3136
#define C_ENC_ 64
#define K_     256
#define BHW_   (B_ * HW_)       // 100352
#define PTS_ROW_ (3 + C_ENC_)   // 67

#define CSTEP_ 64               // channels per pipeline step
#define NSTEP_ (C_IN_ / CSTEP_) // 8

// ---------------------------------------------------------------------------
// k1: transpose conv_w [C_ENC, C_IN] -> Wt [C_IN, C_ENC]
// ---------------------------------------------------------------------------
__global__ __launch_bounds__(256) void k_transpose_w(
        const float* __restrict__ w, float* __restrict__ wt) {
    int i = blockIdx.x * 256 + threadIdx.x;          // 0 .. 32767
    if (i < C_ENC_ * C_IN_) {
        int o = i / C_IN_;
        int c = i % C_IN_;
        wt[c * C_ENC_ + o] = w[i];
    }
}

// async global->LDS: 64 lanes x 4B -> one 256B channel row. LDS dest is
// wave-uniform base + lane*4 (linear), global src per-lane (guide §5).
__device__ __forceinline__ void gload_lds4(const float* g, float* l) {
    __builtin_amdgcn_global_load_lds(
        (const __attribute__((address_space(1))) void*)g,
        (__attribute__((address_space(3))) void*)l, 4, 0, 0);
}

// ---------------------------------------------------------------------------
// k2 v7: 1x1 conv + norm + feats store — 2-phase gload_lds pipeline,
// guide-T3 minimum recipe with BIG steps.
// Failure analysis so far: VALU-issue work is ~46-55us (~= the 42us fp32 FMA
// floor); everything above is stall. v5 (LDS, 16-ch steps) died on 32x
// (vmcnt + 2 barriers) per 512cy of compute; v6 (reg ping-pong) died because
// the allocator (VGPR=44 < 48 live) re-scheduled loads next to uses.
// v7: CSTEP=64 -> per barrier pair: 1024 FMA = 2048 wave-cy of compute;
// stage(s+1) issued BEFORE compute(s); single vmcnt(0)+barrier per step
// (the drain waits on loads issued 2048cy earlier -> ~free). Each channel
// row staged ONCE per block (v4/v6 loaded it 4x). Per-thread ~26 VGPR.
// NUMERICS: per-(pixel,o) chain (bias, c-ascending fmaf) bit-identical to
// all passing rounds -> feats bit-identical. Norm = 4 group partials
// (o-ascending, g-ascending) — identical to passing v5/v6.
// ---------------------------------------------------------------------------
__global__ __launch_bounds__(256) void k_conv_norm(
        const float* __restrict__ F, const float* __restrict__ wt,
        const float* __restrict__ bias, float* __restrict__ norms,
        float* __restrict__ feats) {
    __shared__ float xbuf[2][CSTEP_][64];            // 32 KB double buffer
    __shared__ float nrmp[4][64];                    // 1 KB, conflict-free axis

    int t = threadIdx.x;
    int pix_l = t & 63;
    int g = __builtin_amdgcn_readfirstlane(t >> 6);  // 0..3, wave-uniform
    int pb = blockIdx.x;                             // 0..1567
    int b = pb / 49;                                 // 3136/64 = 49
    int pix0 = (pb % 49) * 64;

    const float* f  = F + (size_t)b * (C_IN_ * HW_) + pix0 + pix_l;
    const float* wg = wt + g * 16;                   // wt layout [c][64]

    float acc[16];
    #pragma unroll
    for (int o = 0; o < 16; ++o) acc[o] = bias[g * 16 + o];

    // prologue: stage step 0 — wave g stages channels g*16 .. g*16+15
    #pragma unroll
    for (int u = 0; u < 16; ++u)
        gload_lds4(f + (size_t)(g * 16 + u) * HW_, &xbuf[0][g * 16 + u][0]);
    asm volatile("s_waitcnt vmcnt(0)" ::: "memory");
    __syncthreads();

    for (int s = 0; s < NSTEP_; ++s) {
        // phase 1: issue stage(s+1) — stays in flight under compute(s)
        if (s + 1 < NSTEP_) {
            int cn = (s + 1) * CSTEP_ + g * 16;
            float* dst = &xbuf[(s + 1) & 1][g * 16][0];
            #pragma unroll
            for (int u = 0; u < 16; ++u)
                gload_lds4(f + (size_t)(cn + u) * HW_, dst + u * 64);
        }
        // phase 2: compute step s from LDS (ds_read_b32: 64 lanes contiguous
        // = conflict-free; W wave-uniform -> s_load)
        {
            const float* xb = &xbuf[s & 1][0][0];
            int cb = s * CSTEP_;
            #pragma unroll 8
            for (int cl = 0; cl < CSTEP_; ++cl) {
                float x = xb[cl * 64 + pix_l];
                #pragma unroll
                for (int o = 0; o < 16; ++o)
                    acc[o] = fmaf(x, wg[(cb + cl) * C_ENC_ + o], acc[o]);
            }
        }
        // phase 3: one drain+barrier per 2048cy of compute (drain ~free:
        // stage(s+1) was issued a full step ago)
        asm volatile("s_waitcnt vmcnt(0)" ::: "memory");
        __syncthreads();
    }

    // feats store: [b][o][pix] -> 16 coalesced dword stores
    #pragma unroll
    for (int o = 0; o < 16; ++o)
        feats[(size_t)(b * C_ENC_ + g * 16 + o) * HW_ + pix0 + pix_l] = acc[o];

    // norm: per-group partial (o ascending), then 4 partials g-ascending
    float p = 0.0f;
    #pragma unroll
    for (int o = 0; o < 16; ++o) p = fmaf(acc[o], acc[o], p);
    nrmp[g][pix_l] = p;
    __syncthreads();

    if (t < 64) {
        float nrm = ((nrmp[0][t] + nrmp[1][t]) + nrmp[2][t]) + nrmp[3][t];
        norms[b * HW_ + pix0 + t] = nrm;
    }
}

// ---------------------------------------------------------------------------
// k3 v2 (unchanged, passed R3-R6): radix-select exact 256th-largest key,
// compact >= T, bitonic-sort 512 -> exact jax.lax.top_k order.
// Also writes the full sw plane.
// ---------------------------------------------------------------------------
__global__ __launch_bounds__(512) void k_topk(
        const float* __restrict__ norms, unsigned int* __restrict__ topk,
        float* __restrict__ sw_out) {
    __shared__ unsigned int keys[HW_];               // 12.25 KB
    __shared__ unsigned int hist[256];
    __shared__ unsigned long long sortbuf[512];      // 4 KB
    __shared__ unsigned int s_prefix, s_need, s_cnt;
    __shared__ unsigned char flags[HW_];

    int b = blockIdx.x;
    int t = threadIdx.x;
    const float* nb = norms + b * HW_;

    for (int i = t; i < HW_; i += 512) {
        keys[i] = __float_as_uint(nb[i]);
        flags[i] = 0;
    }
    if (t == 0) { s_prefix = 0u; s_need = K_; s_cnt = 0u; }
    for (int i = t; i < 512; i += 512) sortbuf[i] = ~0ULL;

    for (int r = 0; r < 4; ++r) {
        if (t < 256) hist[t] = 0u;
        __syncthreads();
        unsigned int pfx = s_prefix;
        int shift = 24 - 8 * r;
        for (int i = t; i < HW_; i += 512) {
            unsigned int k = keys[i];
            bool ok = (r == 0) || ((k >> (32 - 8 * r)) == pfx);
            if (ok) atomicAdd(&hist[(k >> shift) & 0xFFu], 1u);
        }
        __syncthreads();
        if (t < 64) {                                // wave 0: suffix-scan
            unsigned int h0 = hist[4 * t + 0];
            unsigned int h1 = hist[4 * t + 1];
            unsigned int h2 = hist[4 * t + 2];
            unsigned int h3 = hist[4 * t + 3];
            unsigned int tot = h0 + h1 + h2 + h3;
            unsigned int suf = tot;
            #pragma unroll
            for (int off = 1; off < 64; off <<= 1) {
                unsigned int v = __shfl_down(suf, off);
                suf += (t + off < 64) ? v : 0u;
            }
            unsigned int g0 = suf;
            unsigned int g1 = suf - h0;
            unsigned int g2 = g1 - h1;
            unsigned int g3 = g2 - h2;
            unsigned int g4 = g3 - h3;
            unsigned int need = s_need;
            if (g0 >= need && g1 < need) { s_prefix = (pfx << 8) | (4u*t+0u); s_need = need - g1; }
            if (g1 >= need && g2 < need) { s_prefix = (pfx << 8) | (4u*t+1u); s_need = need - g2; }
            if (g2 >= need && g3 < need) { s_prefix = (pfx << 8) | (4u*t+2u); s_need = need - g3; }
            if (g3 >= need && g4 < need) { s_prefix = (pfx << 8) | (4u*t+3u); s_need = need - g4; }
        }
        __syncthreads();
    }
    unsigned int T = s_prefix;

    for (int i = t; i < HW_; i += 512) {
        unsigned int k = keys[i];
        if (k >= T) {
            unsigned int pos = atomicAdd(&s_cnt, 1u);
            if (pos < 512)
                sortbuf[pos] = ((unsigned long long)(~k) << 32) | (unsigned int)i;
        }
    }
    __syncthreads();

    for (int kk = 2; kk <= 512; kk <<= 1) {
        for (int j = kk >> 1; j > 0; j >>= 1) {
            int ixj = t ^ j;
            if (ixj > t) {
                unsigned long long a = sortbuf[t], c = sortbuf[ixj];
                bool up = ((t & kk) == 0);
                if ((a > c) == up) { sortbuf[t] = c; sortbuf[ixj] = a; }
            }
            __syncthreads();
        }
    }

    if (t < K_) {
        unsigned long long e = sortbuf[t];
        unsigned int idx = (unsigned int)(e & 0xFFFFFFFFu);
        topk[b * K_ + t] = idx;
        flags[idx] = 1;
    }
    __syncthreads();

    float* swb = sw_out + b * HW_;
    for (int i = t; i < HW_; i += 512)
        swb[i] = flags[i] ? 1.0f : 0.0f;
}

// ---------------------------------------------------------------------------
// k4 v2 (unchanged): pure gather. One wave per (b,k): lane o reads
// feats[b][o][p], writes the 67-float points row.
// ---------------------------------------------------------------------------
__global__ __launch_bounds__(64) void k_points(
        const float* __restrict__ feats, const unsigned int* __restrict__ topk,
        float* __restrict__ points) {
    int bk = blockIdx.x;                             // 0 .. B*K-1
    int b = bk >> 8;                                 // K = 256
    int o = threadIdx.x;
    unsigned int p = topk[bk];

    float v = feats[(size_t)(b * C_ENC_ + o) * HW_ + p];
    float* row = points + (size_t)bk * PTS_ROW_;
    row[3 + o] = v;
    if (o == 0) {
        row[0] = (float)(p % W_);                    // abs_ (x)
        row[1] = (float)(p / W_);                    // ord_ (y)
        row[2] = 0.0f;                               // depth
    }
}

// ---------------------------------------------------------------------------
// k5 v2 (unchanged): x_out[b][o] = mean over K of feats[b][o][idx_k],
// k ascending (reference order). Indices staged in LDS.
// ---------------------------------------------------------------------------
__global__ __launch_bounds__(64) void k_xout(
        const float* __restrict__ feats, const unsigned int* __restrict__ topk,
        float* __restrict__ xout) {
    __shared__ unsigned int sidx[K_];
    int b = blockIdx.x;
    int t = threadIdx.x;
    for (int r = t; r < K_; r += 64) sidx[r] = topk[b * K_ + r];
    __syncthreads();

    const float* fb = feats + (size_t)(b * C_ENC_ + t) * HW_;
    float s = 0.0f;
    #pragma unroll 8
    for (int k = 0; k < K_; ++k) s += fb[sidx[k]];
    xout[b * C_ENC_ + t] = s * (1.0f / K_);
}

// ---------------------------------------------------------------------------
extern "C" void kernel_launch(void* const* d_in, const int* in_sizes, int n_in,
                              void* d_out, int out_size, void* d_ws, size_t ws_size,
                              hipStream_t stream) {
    const float* F    = (const float*)d_in[0];       // [B, C_IN, H, W]
    const float* w    = (const float*)d_in[1];       // [C_ENC, C_IN]
    const float* bias = (const float*)d_in[2];       // [C_ENC]

    float* out    = (float*)d_out;
    float* xout   = out;                             // [B, C_ENC]      (2048)
    float* sw     = out + B_ * C_ENC_;               // [B, 1, H, W]    (100352)
    float* points = sw + BHW_;                       // [B, K, 67]      (548864)

    // workspace: feats [B,64,HW] 25.7MB | Wt 128KB | norms 392KB | topk 32KB
    float* feats         = (float*)d_ws;
    float* wt            = feats + (size_t)B_ * C_ENC_ * HW_;
    float* norms         = wt + C_IN_ * C_ENC_;
    unsigned int* topk   = (unsigned int*)(norms + BHW_);

    k_transpose_w<<<128, 256, 0, stream>>>(w, wt);
    k_conv_norm  <<<BHW_ / 64, 256, 0, stream>>>(F, wt, bias, norms, feats);
    k_topk       <<<B_, 512, 0, stream>>>(norms, topk, sw);
    k_points     <<<B_ * K_, 64, 0, stream>>>(feats, topk, points);
    k_xout       <<<B_, 64, 0, stream>>>(feats, topk, xout);
}

// Round 8
// 157.177 us; speedup vs baseline: 1.3500x; 1.0289x over previous
//
#include <hip/hip_runtime.h>

// Problem constants (fixed by the reference)
#define B_     32
#define C_IN_  512
#define H_     56
#define W_     56
#define HW_    (H_ * W_)        // 3136
#define C_ENC_ 64
#define K_     256
#define BHW_   (B_ * HW_)       // 100352
#define PTS_ROW_ (3 + C_ENC_)   // 67

#define CSTEP_ 64               // channels per pipeline step
#define NSTEP_ (C_IN_ / CSTEP_) // 8

typedef float f32x2 __attribute__((ext_vector_type(2)));

// ---------------------------------------------------------------------------
// k1: transpose conv_w [C_ENC, C_IN] -> Wt [C_IN, C_ENC]
// ---------------------------------------------------------------------------
__global__ __launch_bounds__(256) void k_transpose_w(
        const float* __restrict__ w, float* __restrict__ wt) {
    int i = blockIdx.x * 256 + threadIdx.x;          // 0 .. 32767
    if (i < C_ENC_ * C_IN_) {
        int o = i / C_IN_;
        int c = i % C_IN_;
        wt[c * C_ENC_ + o] = w[i];
    }
}

// async global->LDS, 16 B per lane (guide Common-mistake #1: width 4->16 was
// +67% on the GEMM ladder). One instr: 64 lanes x 16B = 1 KB = 4 channel rows
// of 64 pixels. LDS dest = wave-uniform base + lane*16 (linear); global src
// per-lane: lane l -> channel +(l>>4), pixel byte +(l&15)*4.
__device__ __forceinline__ void gload_lds16(const float* g, float* l) {
    __builtin_amdgcn_global_load_lds(
        (const __attribute__((address_space(1))) void*)g,
        (__attribute__((address_space(3))) void*)l, 16, 0, 0);
}

// ---------------------------------------------------------------------------
// k2 v8: 1x1 conv + norm + feats store — v7's 2-phase pipeline + two
// orthogonal issue-count levers (structure experiments v4/v5/v7 all ~140us):
//  - gload_lds width 16: 4 instrs/step/wave instead of 16; 1 KB requests
//  - v_pk_fma_f32 via f32x2 + __builtin_elementwise_fma: o-pairs packed,
//    8 pk-FMA per channel instead of 16 FMA (157 TF fp32 = the PACKED rate;
//    scalar fmaf caps at half). W o-pairs are contiguous in wt rows -> s_load
//    pairs, still wave-uniform scalar operands.
// NUMERICS: pk_fma = two independent fp32 FMAs -> per-(pixel,o) chain
// (bias, c-ascending) bit-identical to all passing rounds -> feats
// bit-identical. Norm: evens/odds packed partials then .x+.y, then 4 group
// partials g-ascending — same ~1e-6 regroup class as v5's change (passed 3x).
// ---------------------------------------------------------------------------
__global__ __launch_bounds__(256) void k_conv_norm(
        const float* __restrict__ F, const float* __restrict__ wt,
        const float* __restrict__ bias, float* __restrict__ norms,
        float* __restrict__ feats) {
    __shared__ float xbuf[2][CSTEP_][64];            // 32 KB double buffer
    __shared__ float nrmp[4][64];                    // 1 KB

    int t = threadIdx.x;
    int pix_l = t & 63;
    int g = __builtin_amdgcn_readfirstlane(t >> 6);  // 0..3, wave-uniform
    int pb = blockIdx.x;                             // 0..1567
    int b = pb / 49;                                 // 3136/64 = 49
    int pix0 = (pb % 49) * 64;

    // per-lane base for compute-side reads (one pixel per lane)
    const float* f = F + (size_t)b * (C_IN_ * HW_) + pix0 + pix_l;
    // per-lane base for 16B staging: lane l covers channel +(l>>4),
    // pixel bytes (l&15)*16 within this block's 64-pixel row
    const float* fs = F + (size_t)b * (C_IN_ * HW_)
                        + (size_t)(pix_l >> 4) * HW_ + pix0 + (pix_l & 15) * 4;

    float acc_dummy; (void)acc_dummy;
    f32x2 acc2[8];
    #pragma unroll
    for (int j = 0; j < 8; ++j) {
        acc2[j][0] = bias[g * 16 + 2 * j];
        acc2[j][1] = bias[g * 16 + 2 * j + 1];
    }

    // prologue: stage step 0 — wave g stages channels g*16..g*16+15
    // via 4 x 16B instrs (each covers 4 channel rows)
    #pragma unroll
    for (int u = 0; u < 4; ++u)
        gload_lds16(fs + (size_t)(g * 16 + u * 4) * HW_,
                    &xbuf[0][g * 16 + u * 4][0]);
    asm volatile("s_waitcnt vmcnt(0)" ::: "memory");
    __syncthreads();

    for (int s = 0; s < NSTEP_; ++s) {
        // phase 1: issue stage(s+1) — in flight under compute(s)
        if (s + 1 < NSTEP_) {
            int cn = (s + 1) * CSTEP_ + g * 16;
            float* dst = &xbuf[(s + 1) & 1][g * 16][0];
            #pragma unroll
            for (int u = 0; u < 4; ++u)
                gload_lds16(fs + (size_t)(cn + u * 4) * HW_, dst + u * 4 * 64);
        }
        // phase 2: compute step s from LDS; 8 pk-FMA per channel
        {
            const float* xb = &xbuf[s & 1][0][0];
            int cb = s * CSTEP_;
            #pragma unroll 8
            for (int cl = 0; cl < CSTEP_; ++cl) {
                float x = xb[cl * 64 + pix_l];
                f32x2 x2; x2[0] = x; x2[1] = x;
                const f32x2* w2row = reinterpret_cast<const f32x2*>(
                        wt + (size_t)(cb + cl) * C_ENC_ + g * 16);
                #pragma unroll
                for (int j = 0; j < 8; ++j)
                    acc2[j] = __builtin_elementwise_fma(x2, w2row[j], acc2[j]);
            }
        }
        // phase 3: one drain+barrier per step (loads had a full step to land)
        asm volatile("s_waitcnt vmcnt(0)" ::: "memory");
        __syncthreads();
    }

    // feats store: [b][o][pix] -> 16 coalesced dword stores
    #pragma unroll
    for (int j = 0; j < 8; ++j) {
        feats[(size_t)(b * C_ENC_ + g * 16 + 2 * j) * HW_ + pix0 + pix_l] = acc2[j][0];
        feats[(size_t)(b * C_ENC_ + g * 16 + 2 * j + 1) * HW_ + pix0 + pix_l] = acc2[j][1];
    }

    // norm: packed partial (evens/odds), then .x+.y, then 4 group partials
    f32x2 p2; p2[0] = 0.0f; p2[1] = 0.0f;
    #pragma unroll
    for (int j = 0; j < 8; ++j)
        p2 = __builtin_elementwise_fma(acc2[j], acc2[j], p2);
    nrmp[g][pix_l] = p2[0] + p2[1];
    __syncthreads();

    if (t < 64) {
        float nrm = ((nrmp[0][t] + nrmp[1][t]) + nrmp[2][t]) + nrmp[3][t];
        norms[b * HW_ + pix0 + t] = nrm;
    }
}

// ---------------------------------------------------------------------------
// k3 v2 (unchanged, passed R3-R7): radix-select exact 256th-largest key,
// compact >= T, bitonic-sort 512 -> exact jax.lax.top_k order.
// Also writes the full sw plane.
// ---------------------------------------------------------------------------
__global__ __launch_bounds__(512) void k_topk(
        const float* __restrict__ norms, unsigned int* __restrict__ topk,
        float* __restrict__ sw_out) {
    __shared__ unsigned int keys[HW_];               // 12.25 KB
    __shared__ unsigned int hist[256];
    __shared__ unsigned long long sortbuf[512];      // 4 KB
    __shared__ unsigned int s_prefix, s_need, s_cnt;
    __shared__ unsigned char flags[HW_];

    int b = blockIdx.x;
    int t = threadIdx.x;
    const float* nb = norms + b * HW_;

    for (int i = t; i < HW_; i += 512) {
        keys[i] = __float_as_uint(nb[i]);
        flags[i] = 0;
    }
    if (t == 0) { s_prefix = 0u; s_need = K_; s_cnt = 0u; }
    for (int i = t; i < 512; i += 512) sortbuf[i] = ~0ULL;

    for (int r = 0; r < 4; ++r) {
        if (t < 256) hist[t] = 0u;
        __syncthreads();
        unsigned int pfx = s_prefix;
        int shift = 24 - 8 * r;
        for (int i = t; i < HW_; i += 512) {
            unsigned int k = keys[i];
            bool ok = (r == 0) || ((k >> (32 - 8 * r)) == pfx);
            if (ok) atomicAdd(&hist[(k >> shift) & 0xFFu], 1u);
        }
        __syncthreads();
        if (t < 64) {                                // wave 0: suffix-scan
            unsigned int h0 = hist[4 * t + 0];
            unsigned int h1 = hist[4 * t + 1];
            unsigned int h2 = hist[4 * t + 2];
            unsigned int h3 = hist[4 * t + 3];
            unsigned int tot = h0 + h1 + h2 + h3;
            unsigned int suf = tot;
            #pragma unroll
            for (int off = 1; off < 64; off <<= 1) {
                unsigned int v = __shfl_down(suf, off);
                suf += (t + off < 64) ? v : 0u;
            }
            unsigned int g0 = suf;
            unsigned int g1 = suf - h0;
            unsigned int g2 = g1 - h1;
            unsigned int g3 = g2 - h2;
            unsigned int g4 = g3 - h3;
            unsigned int need = s_need;
            if (g0 >= need && g1 < need) { s_prefix = (pfx << 8) | (4u*t+0u); s_need = need - g1; }
            if (g1 >= need && g2 < need) { s_prefix = (pfx << 8) | (4u*t+1u); s_need = need - g2; }
            if (g2 >= need && g3 < need) { s_prefix = (pfx << 8) | (4u*t+2u); s_need = need - g3; }
            if (g3 >= need && g4 < need) { s_prefix = (pfx << 8) | (4u*t+3u); s_need = need - g4; }
        }
        __syncthreads();
    }
    unsigned int T = s_prefix;

    for (int i = t; i < HW_; i += 512) {
        unsigned int k = keys[i];
        if (k >= T) {
            unsigned int pos = atomicAdd(&s_cnt, 1u);
            if (pos < 512)
                sortbuf[pos] = ((unsigned long long)(~k) << 32) | (unsigned int)i;
        }
    }
    __syncthreads();

    for (int kk = 2; kk <= 512; kk <<= 1) {
        for (int j = kk >> 1; j > 0; j >>= 1) {
            int ixj = t ^ j;
            if (ixj > t) {
                unsigned long long a = sortbuf[t], c = sortbuf[ixj];
                bool up = ((t & kk) == 0);
                if ((a > c) == up) { sortbuf[t] = c; sortbuf[ixj] = a; }
            }
            __syncthreads();
        }
    }

    if (t < K_) {
        unsigned long long e = sortbuf[t];
        unsigned int idx = (unsigned int)(e & 0xFFFFFFFFu);
        topk[b * K_ + t] = idx;
        flags[idx] = 1;
    }
    __syncthreads();

    float* swb = sw_out + b * HW_;
    for (int i = t; i < HW_; i += 512)
        swb[i] = flags[i] ? 1.0f : 0.0f;
}

// ---------------------------------------------------------------------------
// k4 v2 (unchanged): pure gather. One wave per (b,k): lane o reads
// feats[b][o][p], writes the 67-float points row.
// ---------------------------------------------------------------------------
__global__ __launch_bounds__(64) void k_points(
        const float* __restrict__ feats, const unsigned int* __restrict__ topk,
        float* __restrict__ points) {
    int bk = blockIdx.x;                             // 0 .. B*K-1
    int b = bk >> 8;                                 // K = 256
    int o = threadIdx.x;
    unsigned int p = topk[bk];

    float v = feats[(size_t)(b * C_ENC_ + o) * HW_ + p];
    float* row = points + (size_t)bk * PTS_ROW_;
    row[3 + o] = v;
    if (o == 0) {
        row[0] = (float)(p % W_);                    // abs_ (x)
        row[1] = (float)(p / W_);                    // ord_ (y)
        row[2] = 0.0f;                               // depth
    }
}

// ---------------------------------------------------------------------------
// k5 v2 (unchanged): x_out[b][o] = mean over K of feats[b][o][idx_k],
// k ascending (reference order). Indices staged in LDS.
// ---------------------------------------------------------------------------
__global__ __launch_bounds__(64) void k_xout(
        const float* __restrict__ feats, const unsigned int* __restrict__ topk,
        float* __restrict__ xout) {
    __shared__ unsigned int sidx[K_];
    int b = blockIdx.x;
    int t = threadIdx.x;
    for (int r = t; r < K_; r += 64) sidx[r] = topk[b * K_ + r];
    __syncthreads();

    const float* fb = feats + (size_t)(b * C_ENC_ + t) * HW_;
    float s = 0.0f;
    #pragma unroll 8
    for (int k = 0; k < K_; ++k) s += fb[sidx[k]];
    xout[b * C_ENC_ + t] = s * (1.0f / K_);
}

// ---------------------------------------------------------------------------
extern "C" void kernel_launch(void* const* d_in, const int* in_sizes, int n_in,
                              void* d_out, int out_size, void* d_ws, size_t ws_size,
                              hipStream_t stream) {
    const float* F    = (const float*)d_in[0];       // [B, C_IN, H, W]
    const float* w    = (const float*)d_in[1];       // [C_ENC, C_IN]
    const float* bias = (const float*)d_in[2];       // [C_ENC]

    float* out    = (float*)d_out;
    float* xout   = out;                             // [B, C_ENC]      (2048)
    float* sw     = out + B_ * C_ENC_;               // [B, 1, H, W]    (100352)
    float* points = sw + BHW_;                       // [B, K, 67]      (548864)

    // workspace: feats [B,64,HW] 25.7MB | Wt 128KB | norms 392KB | topk 32KB
    float* feats         = (float*)d_ws;
    float* wt            = feats + (size_t)B_ * C_ENC_ * HW_;
    float* norms         = wt + C_IN_ * C_ENC_;
    unsigned int* topk   = (unsigned int*)(norms + BHW_);

    k_transpose_w<<<128, 256, 0, stream>>>(w, wt);
    k_conv_norm  <<<BHW_ / 64, 256, 0, stream>>>(F, wt, bias, norms, feats);
    k_topk       <<<B_, 512, 0, stream>>>(norms, topk, sw);
    k_points     <<<B_ * K_, 64, 0, stream>>>(feats, topk, points);
    k_xout       <<<B_, 64, 0, stream>>>(feats, topk, xout);
}